// Round 2
// baseline (351.145 us; speedup 1.0000x reference)
//
#include <hip/hip_runtime.h>
#include <hip/hip_bf16.h>
#include <stdint.h>

// Problem constants (B=4, T=2048, D=256, M=128, L=16, P=2048)
#define TAU 0.35f   // bf16-path score uncertainty window for fp32 refinement

typedef __attribute__((ext_vector_type(8))) short bf16x8;
typedef __attribute__((ext_vector_type(4))) float f32x4;

__device__ __forceinline__ unsigned short f2bf(float f) {
  __bf16 h = (__bf16)f;
  return __builtin_bit_cast(unsigned short, h);
}
__device__ __forceinline__ float bf2f(unsigned short u) {
  unsigned int v = ((unsigned int)u) << 16;
  return __builtin_bit_cast(float, v);
}
__device__ __forceinline__ void async_copy16(const void* g, void* l) {
  __builtin_amdgcn_global_load_lds(
      (const __attribute__((address_space(1))) unsigned int*)g,
      (__attribute__((address_space(3))) unsigned int*)l, 16, 0, 0);
}

// ---------------------------------------------------------------------------
// K0: transpose+convert x -> xt[b][d][t] (bf16, K-contig); w1 -> w1t[n][k]
//     (bf16, K-contig); init logits with b2; zero njobs.
// ---------------------------------------------------------------------------
__global__ __launch_bounds__(256) void k_prep(
    const float* __restrict__ x, const float* __restrict__ w1,
    const float* __restrict__ b2,
    unsigned short* __restrict__ xt, unsigned short* __restrict__ w1t,
    float* __restrict__ logits, int* __restrict__ njobs) {
  __shared__ float tileS[64][65];
  int bx = blockIdx.x, tid = threadIdx.x;
  if (bx == 0 && tid == 0) *njobs = 0;
  if (bx < 64) {  // logits init: 16384 floats
    int i = bx * 256 + tid;
    logits[i] = b2[i & 1];
  }
  int j = tid & 63, i0 = tid >> 6;
  if (bx < 512) {                       // x tiles: b(4) * t-tiles(32) * d-tiles(4)
    int b = bx >> 7, t6 = (bx >> 2) & 31, d6 = bx & 3;
    const float* src = x + ((size_t)b * 2048 + (size_t)t6 * 64) * 256 + d6 * 64;
    for (int i = i0; i < 64; i += 4) tileS[i][j] = src[(size_t)i * 256 + j];
    __syncthreads();
    unsigned short* dst = xt + ((size_t)b * 256 + (size_t)d6 * 64) * 2048 + t6 * 64;
    for (int r = i0; r < 64; r += 4) dst[(size_t)r * 2048 + j] = f2bf(tileS[j][r]);
  } else {                              // w1 tiles: k-tiles(12) * n-tiles(4)
    int wt = bx - 512;
    int k6 = wt >> 2, n6 = wt & 3;
    const float* src = w1 + ((size_t)k6 * 64) * 256 + n6 * 64;
    for (int i = i0; i < 64; i += 4) tileS[i][j] = src[(size_t)i * 256 + j];
    __syncthreads();
    unsigned short* dst = w1t + ((size_t)n6 * 64) * 768 + k6 * 64;
    for (int r = i0; r < 64; r += 4) dst[(size_t)r * 768 + j] = f2bf(tileS[j][r]);
  }
}

// ---------------------------------------------------------------------------
// K1: head_rep/tail_rep = [head;tail] @ x   (bf16 MFMA, fp32 out)
// 64x64 tiles. This round: barrier amortization, NO inline asm.
//  - K processed in PAIRS of 64-k chunks per __syncthreads: 4 B LDS buffers
//    (XOR-swizzled, staged via global_load_lds), A direct global->reg with
//    2-chunk-deep register prefetch (fp32, converted to bf16 in-reg).
//  - 16 barriers instead of 32: the vmcnt(0) drain the compiler emits at
//    each __syncthreads is paid half as often; prefetch for pair s+1 is
//    issued at pair s and completes at the barrier (1-slot lead).
// grid = 1024 (4 blocks/CU, 32KB LDS/block). ntile = bx>>8 so stride-256
// siblings share an XCD under round-robin dispatch -> A fetched once.
// ---------------------------------------------------------------------------
__global__ __launch_bounds__(256, 4) void k_gemm_rep(
    const float* __restrict__ head, const float* __restrict__ tail,
    const unsigned short* __restrict__ xt,
    float* __restrict__ hrep, float* __restrict__ trep) {
  __shared__ unsigned short Bs[4][4096];  // chunk(col,k8) at col*8 + (k8^(col&7))
  int bx = blockIdx.x;
  int ntile = bx >> 8;              // 0..3
  int g = bx & 255;
  int b = g >> 6, mtile = g & 63;   // mtile<32: head, else tail
  const float* Asrc = ((mtile < 32) ? head : tail) +
                      ((size_t)(b * 2048 + (mtile & 31) * 64)) * 2048;
  float* Crep = (mtile < 32) ? hrep : trep;
  const unsigned short* Bsrc = xt + ((size_t)(b * 256 + ntile * 64)) * 2048;

  int tid = threadIdx.x, lane = tid & 63, w = tid >> 6;

  // ---- B staging via global_load_lds (wave w stages cols w*16..w*16+15) ----
  const unsigned short* bg0;
  const unsigned short* bg1;
  int bdst0, bdst1;
  {
    int colofs0 = (lane >> 3);
    int colofs1 = 8 + (lane >> 3);
    int k80 = (lane & 7) ^ (colofs0 & 7);       // XOR swizzle
    int k81 = (lane & 7) ^ (colofs1 & 7);
    bg0 = Bsrc + (size_t)(w * 16 + colofs0) * 2048 + k80 * 8;
    bg1 = Bsrc + (size_t)(w * 16 + colofs1) * 2048 + k81 * 8;
    bdst0 = (w * 128 + lane) * 8;               // lane-linear LDS dest
    bdst1 = (w * 128 + 64 + lane) * 8;
  }

  // ---- fragment read indices (B) ----
  int sw0 = (lane >> 4) ^ (lane & 7);           // kh=0 swizzled k8
  int sw1 = (4 + (lane >> 4)) ^ (lane & 7);     // kh=1
  int colc[4];
#pragma unroll
  for (int ct = 0; ct < 4; ++ct) colc[ct] = (ct * 16 + (lane & 15)) * 8;

  // ---- A: direct fragment pointer. lane holds A[row][k0..k0+8) per kh ----
  // row = w*16 + (lane&15); a0: k = (lane>>4)*8 ; a1: +32
  const float* anext =
      Asrc + (size_t)(w * 16 + (lane & 15)) * 2048 + ((lane >> 4) << 3);

  f32x4 acc[4];
#pragma unroll
  for (int ct = 0; ct < 4; ++ct) acc[ct] = (f32x4){0.f, 0.f, 0.f, 0.f};

  auto STAGEB = [&](int buf) {   // stages one 64-k chunk, advances bg
    async_copy16(bg0, &Bs[buf][bdst0]); bg0 += 64;
    async_copy16(bg1, &Bs[buf][bdst1]); bg1 += 64;
  };
  auto LOADA = [&](float4* av) { // loads one 64-k A chunk to regs, advances
    const float4* ap = (const float4*)anext;
    av[0] = ap[0]; av[1] = ap[1];   // k .. k+8
    av[2] = ap[8]; av[3] = ap[9];   // k+32 .. k+40
    anext += 64;
  };
  auto MMA = [&](int buf, const float4* av) {   // convert + 8 MFMA
    bf16x8 f0, f1;
    f0[0] = (short)f2bf(av[0].x); f0[1] = (short)f2bf(av[0].y);
    f0[2] = (short)f2bf(av[0].z); f0[3] = (short)f2bf(av[0].w);
    f0[4] = (short)f2bf(av[1].x); f0[5] = (short)f2bf(av[1].y);
    f0[6] = (short)f2bf(av[1].z); f0[7] = (short)f2bf(av[1].w);
    f1[0] = (short)f2bf(av[2].x); f1[1] = (short)f2bf(av[2].y);
    f1[2] = (short)f2bf(av[2].z); f1[3] = (short)f2bf(av[2].w);
    f1[4] = (short)f2bf(av[3].x); f1[5] = (short)f2bf(av[3].y);
    f1[6] = (short)f2bf(av[3].z); f1[7] = (short)f2bf(av[3].w);
    const unsigned short* B_ = Bs[buf];
#pragma unroll
    for (int ct = 0; ct < 4; ++ct) {
      bf16x8 b0 = *(const bf16x8*)&B_[(colc[ct] + sw0) * 8];
      acc[ct] = __builtin_amdgcn_mfma_f32_16x16x32_bf16(f0, b0, acc[ct], 0, 0, 0);
    }
#pragma unroll
    for (int ct = 0; ct < 4; ++ct) {
      bf16x8 b1 = *(const bf16x8*)&B_[(colc[ct] + sw1) * 8];
      acc[ct] = __builtin_amdgcn_mfma_f32_16x16x32_bf16(f1, b1, acc[ct], 0, 0, 0);
    }
  };

  float4 avA0[4], avA1[4], avB0[4], avB1[4];
  // prologue: pair 0 -> bufs {0,1} + regs avA*
  STAGEB(0); STAGEB(1);
  LOADA(avA0); LOADA(avA1);
  __syncthreads();   // drain: pair 0 staged + A regs in hand

  for (int t = 0; t < 8; ++t) {
    // ---- slot s=2t: consume bufs {0,1}/avA*; prefetch pair s+1 -> {2,3}/avB* ----
    STAGEB(2); STAGEB(3);
    LOADA(avB0); LOADA(avB1);
    MMA(0, avA0);
    MMA(1, avA1);
    __syncthreads();   // pair s+1 staged; reads of {0,1} done
    // ---- slot s=2t+1: consume bufs {2,3}/avB*; prefetch -> {0,1}/avA* ----
    if (t < 7) {
      STAGEB(0); STAGEB(1);
      LOADA(avA0); LOADA(avA1);
    }
    MMA(2, avB0);
    MMA(3, avB1);
    __syncthreads();
  }

  // epilogue: C layout col=lane&15, row=(lane>>4)*4+i
  size_t prow = (size_t)b * 2048 + (size_t)(mtile & 31) * 64 + w * 16 + ((lane >> 4) << 2);
  int cb = ntile * 64 + (lane & 15);
#pragma unroll
  for (int ct = 0; ct < 4; ++ct)
#pragma unroll
    for (int i = 0; i < 4; ++i)
      Crep[(prow + i) * 256 + cb + ct * 16] = acc[ct][i];
}

// ---------------------------------------------------------------------------
// K2pre: featbf[p][0:256]=h, [256:512]=t, [512:768]=h*t  (bf16)
// ---------------------------------------------------------------------------
__global__ __launch_bounds__(256) void k_feat(
    const float* __restrict__ hrep, const float* __restrict__ trep,
    unsigned short* __restrict__ featbf) {
  int gid = blockIdx.x * 256 + threadIdx.x;
  int p = gid >> 6, d0 = (gid & 63) * 4;
  float4 h4 = *(const float4*)&hrep[(size_t)p * 256 + d0];
  float4 t4 = *(const float4*)&trep[(size_t)p * 256 + d0];
  ushort4 a, bb, c;
  a.x = f2bf(h4.x); a.y = f2bf(h4.y); a.z = f2bf(h4.z); a.w = f2bf(h4.w);
  bb.x = f2bf(t4.x); bb.y = f2bf(t4.y); bb.z = f2bf(t4.z); bb.w = f2bf(t4.w);
  c.x = f2bf(h4.x * t4.x); c.y = f2bf(h4.y * t4.y);
  c.z = f2bf(h4.z * t4.z); c.w = f2bf(h4.w * t4.w);
  *(ushort4*)&featbf[(size_t)p * 768 + d0] = a;
  *(ushort4*)&featbf[(size_t)p * 768 + 256 + d0] = bb;
  *(ushort4*)&featbf[(size_t)p * 768 + 512 + d0] = c;
}

// ---------------------------------------------------------------------------
// K2: relu(feat @ w1 + b1) @ w2 + b2 -> logits (fused; atomicAdd partials).
// 64x64 tiles, BK=64, dbuf, all staging via global_load_lds (XOR swizzle).
// grid = 512 (2/CU). ntile = bx>>7 so siblings share XCD.
// ---------------------------------------------------------------------------
__global__ __launch_bounds__(256, 4) void k_gemm_mlp(
    const unsigned short* __restrict__ featb, const unsigned short* __restrict__ w1t,
    const float* __restrict__ b1, const float* __restrict__ w2,
    float* __restrict__ logits) {
  __shared__ unsigned short As[2][4096], Bs[2][4096];
  int bx = blockIdx.x;
  int ntile = bx >> 7;   // 0..3
  int mtile = bx & 127;  // 0..127
  int tid = threadIdx.x, lane = tid & 63, w = tid >> 6;

  const unsigned short* ag[2];
  const unsigned short* bgp[2];
  int dofs[2];
#pragma unroll
  for (int a = 0; a < 2; ++a) {
    int rowofs = a * 8 + (lane >> 3);
    int k8 = (lane & 7) ^ (rowofs & 7);
    ag[a] = featb + (size_t)(mtile * 64 + w * 16 + rowofs) * 768 + k8 * 8;
    bgp[a] = w1t + (size_t)(ntile * 64 + w * 16 + rowofs) * 768 + k8 * 8;
    dofs[a] = (w * 128 + a * 64 + lane) * 8;
  }
  int sw0 = (lane >> 4) ^ (lane & 7);
  int sw1 = (4 + (lane >> 4)) ^ (lane & 7);
  int arowc = (w * 16 + (lane & 15)) * 8;
  int colc[4];
#pragma unroll
  for (int ct = 0; ct < 4; ++ct) colc[ct] = (ct * 16 + (lane & 15)) * 8;

  f32x4 acc[4];
#pragma unroll
  for (int ct = 0; ct < 4; ++ct) acc[ct] = (f32x4){0.f, 0.f, 0.f, 0.f};

#pragma unroll
  for (int a = 0; a < 2; ++a) {
    async_copy16(ag[a], &As[0][dofs[a]]); ag[a] += 64;
    async_copy16(bgp[a], &Bs[0][dofs[a]]); bgp[a] += 64;
  }
  __syncthreads();

  for (int it = 0; it < 12; ++it) {
    int cur = it & 1, nxt = cur ^ 1;
    if (it < 11) {
#pragma unroll
      for (int a = 0; a < 2; ++a) {
        async_copy16(ag[a], &As[nxt][dofs[a]]); ag[a] += 64;
        async_copy16(bgp[a], &Bs[nxt][dofs[a]]); bgp[a] += 64;
      }
    }
    const unsigned short* A_ = As[cur];
    const unsigned short* B_ = Bs[cur];
    bf16x8 a0 = *(const bf16x8*)&A_[(arowc + sw0) * 8];
    bf16x8 a1 = *(const bf16x8*)&A_[(arowc + sw1) * 8];
#pragma unroll
    for (int ct = 0; ct < 4; ++ct) {
      bf16x8 b0 = *(const bf16x8*)&B_[(colc[ct] + sw0) * 8];
      acc[ct] = __builtin_amdgcn_mfma_f32_16x16x32_bf16(a0, b0, acc[ct], 0, 0, 0);
    }
#pragma unroll
    for (int ct = 0; ct < 4; ++ct) {
      bf16x8 b1 = *(const bf16x8*)&B_[(colc[ct] + sw1) * 8];
      acc[ct] = __builtin_amdgcn_mfma_f32_16x16x32_bf16(a1, b1, acc[ct], 0, 0, 0);
    }
    __syncthreads();
  }

  // epilogue: relu(+b1), dot with w2 cols, reduce over the 16-lane col group
  float bv[4], w20[4], w21[4];
#pragma unroll
  for (int ct = 0; ct < 4; ++ct) {
    int col = ntile * 64 + ct * 16 + (lane & 15);
    bv[ct] = b1[col]; w20[ct] = w2[col * 2]; w21[ct] = w2[col * 2 + 1];
  }
#pragma unroll
  for (int i = 0; i < 4; ++i) {
    float s0 = 0.f, s1 = 0.f;
#pragma unroll
    for (int ct = 0; ct < 4; ++ct) {
      float r = fmaxf(acc[ct][i] + bv[ct], 0.f);
      s0 += r * w20[ct]; s1 += r * w21[ct];
    }
#pragma unroll
    for (int off = 1; off < 16; off <<= 1) {
      s0 += __shfl_xor(s0, off); s1 += __shfl_xor(s1, off);
    }
    if ((lane & 15) == 0) {
      int row = mtile * 64 + w * 16 + ((lane >> 4) << 2) + i;
      atomicAdd(&logits[row * 2], s0);
      atomicAdd(&logits[row * 2 + 1], s1);
    }
  }
}

// ---------------------------------------------------------------------------
// K3b: per-mention top-1 + uncertainty set; emit refine jobs
// ---------------------------------------------------------------------------
__global__ void k_select(const float* __restrict__ logits, int* __restrict__ idxv,
                         float* __restrict__ mval, int* __restrict__ cmask,
                         int* __restrict__ njobs, int* __restrict__ jobs) {
  int q = blockIdx.x * 256 + threadIdx.x;
  if (q >= 512) return;
  int base = q * 16;
  float s[16];
#pragma unroll
  for (int i = 0; i < 16; ++i) s[i] = logits[(size_t)(base + i) * 2 + 1];
  float best = s[0]; int bi = 0;
#pragma unroll
  for (int i = 1; i < 16; ++i) if (s[i] > best) { best = s[i]; bi = i; }
  int mask = 0, cnt = 0;
#pragma unroll
  for (int i = 0; i < 16; ++i) if (s[i] > best - TAU) { mask |= 1 << i; ++cnt; }
  idxv[q] = bi; mval[q] = best;
  if (cnt > 1) {
    cmask[q] = mask;
    for (int i = 0; i < 16; ++i)
      if ((mask >> i) & 1) { int j = atomicAdd(njobs, 1); jobs[j] = base + i; }
  } else cmask[q] = 0;
}

// ---------------------------------------------------------------------------
// K3c: fp32 exact score recompute for uncertain candidate pairs
// ---------------------------------------------------------------------------
__global__ __launch_bounds__(1024) void k_refine(
    const int* __restrict__ njobs, const int* __restrict__ jobs,
    const float* __restrict__ head, const float* __restrict__ tail,
    const float* __restrict__ x, const float* __restrict__ w1,
    const float* __restrict__ b1, const float* __restrict__ w2,
    const float* __restrict__ b2, float* __restrict__ refined) {
  __shared__ float hrow[2048], trow[2048], feat[768], red[1024], red2[1024];
  int tid = threadIdx.x, seg = tid >> 8, d = tid & 255;
  int nj = *njobs;
  for (int job = blockIdx.x; job < nj; job += gridDim.x) {
    int code = jobs[job];
    int b = code >> 11, p = code & 2047;
    if (tid < 512)
      *(float4*)&hrow[tid * 4] = *(const float4*)&head[((size_t)(b * 2048 + p)) * 2048 + tid * 4];
    else {
      int u = tid - 512;
      *(float4*)&trow[u * 4] = *(const float4*)&tail[((size_t)(b * 2048 + p)) * 2048 + u * 4];
    }
    __syncthreads();
    float hr = 0.f, tr = 0.f;
    const float* xb = x + ((size_t)b * 2048) * 256 + d;
#pragma unroll 8
    for (int t = seg * 512; t < seg * 512 + 512; ++t) {
      float xv = xb[(size_t)t * 256];
      hr += hrow[t] * xv; tr += trow[t] * xv;
    }
    red[tid] = hr; red2[tid] = tr;
    __syncthreads();
    if (seg == 0) {
      float fh = red[d] + red[256 + d] + red[512 + d] + red[768 + d];
      float ft = red2[d] + red2[256 + d] + red2[512 + d] + red2[768 + d];
      feat[d] = fh; feat[256 + d] = ft; feat[512 + d] = fh * ft;
    }
    __syncthreads();
    float hp = 0.f;
    for (int ii = seg * 192; ii < seg * 192 + 192; ++ii) hp += feat[ii] * w1[(size_t)ii * 256 + d];
    red[tid] = hp;
    __syncthreads();
    if (seg == 0) {
      float hj = b1[d] + red[d] + red[256 + d] + red[512 + d] + red[768 + d];
      hj = fmaxf(hj, 0.f);
      red2[d] = hj * w2[d * 2 + 1];
    }
    __syncthreads();
    for (int s = 128; s > 0; s >>= 1) {
      if (tid < s) red2[tid] += red2[tid + s];
      __syncthreads();
    }
    if (tid == 0) refined[code] = red2[0] + b2[1];
    __syncthreads();
  }
}

// ---------------------------------------------------------------------------
// K4a: rep_m[q][d] = tail_rep[q*16+argmax][d] * max_val
// ---------------------------------------------------------------------------
__global__ __launch_bounds__(256) void k_repm(
    const int* __restrict__ idxv, const float* __restrict__ mval,
    const int* __restrict__ cmask, const float* __restrict__ refined,
    const float* __restrict__ trep, float* __restrict__ repm) {
  int q = blockIdx.x, d = threadIdx.x;
  int mask = cmask[q]; int bi; float v;
  if (mask) {
    bi = -1; v = -1e30f;
    for (int i = 0; i < 16; ++i)
      if ((mask >> i) & 1) { float s = refined[q * 16 + i]; if (s > v) { v = s; bi = i; } }
  } else { bi = idxv[q]; v = mval[q]; }
  repm[(size_t)q * 256 + d] = trep[((size_t)q * 16 + bi) * 256 + d] * v;
}

// ---------------------------------------------------------------------------
// K4b: out[b][t][d] = x + sum_m cmp[b][m][t] * rep_m[b][m][d]  (512 blocks)
// ---------------------------------------------------------------------------
__global__ __launch_bounds__(256) void k_merge(
    const float* __restrict__ cmp, const float* __restrict__ repm,
    const float* __restrict__ x, float* __restrict__ out) {
  __shared__ float cl[128 * 16];
  int bx = blockIdx.x, b = bx >> 7, t0 = (bx & 127) * 16;
  int tid = threadIdx.x;
#pragma unroll
  for (int it = 0; it < 2; ++it) {
    int f = it * 256 + tid;
    int row = f >> 2, c4 = (f & 3) * 4;
    *(float4*)&cl[row * 16 + c4] =
        *(const float4*)&cmp[((size_t)(b * 128 + row)) * 2048 + t0 + c4];
  }
  __syncthreads();
  float acc[16];
#pragma unroll
  for (int i = 0; i < 16; ++i) acc[i] = 0.f;
  int d = tid;
  for (int m = 0; m < 128; ++m) {
    float rv = repm[(size_t)(b * 128 + m) * 256 + d];
    const float4* c4p = (const float4*)&cl[m * 16];
#pragma unroll
    for (int jj = 0; jj < 4; ++jj) {
      float4 c = c4p[jj];
      acc[jj * 4] += c.x * rv; acc[jj * 4 + 1] += c.y * rv;
      acc[jj * 4 + 2] += c.z * rv; acc[jj * 4 + 3] += c.w * rv;
    }
  }
  const float* xb = x + ((size_t)(b * 2048 + t0)) * 256 + d;
  float* ob = out + ((size_t)(b * 2048 + t0)) * 256 + d;
#pragma unroll
  for (int tt = 0; tt < 16; ++tt) ob[(size_t)tt * 256] = xb[(size_t)tt * 256] + acc[tt];
}

// ---------------------------------------------------------------------------
// K5: masked KLDiv mean loss (single block)
// ---------------------------------------------------------------------------
__global__ __launch_bounds__(1024) void k_loss(
    const float* __restrict__ logits, const float* __restrict__ lab,
    const unsigned char* __restrict__ mask, float* __restrict__ out_loss) {
  __shared__ float rs[1024], rc[1024];
  int tid = threadIdx.x;
  float sum = 0.f, cnt = 0.f;
  for (int p = tid; p < 8192; p += 1024) {
    float l0 = logits[(size_t)p * 2], l1 = logits[(size_t)p * 2 + 1];
    float a0 = lab[(size_t)p * 2], a1 = lab[(size_t)p * 2 + 1];
    float mx = fmaxf(l0, l1);
    float lse = mx + logf(expf(l0 - mx) + expf(l1 - mx));
    float pw = 0.f;
    if (a0 > 0.f) pw += a0 * logf(fmaxf(a0, 1e-38f));
    if (a1 > 0.f) pw += a1 * logf(fmaxf(a1, 1e-38f));
    pw -= a0 * (l0 - lse) + a1 * (l1 - lse);
    if (mask[p]) { sum += pw; cnt += 1.f; }
  }
  rs[tid] = sum; rc[tid] = cnt;
  __syncthreads();
  for (int s = 512; s > 0; s >>= 1) {
    if (tid < s) { rs[tid] += rs[tid + s]; rc[tid] += rc[tid + s]; }
    __syncthreads();
  }
  if (tid == 0) *out_loss = rs[0] / (rc[0] * 2.0f);
}

// ---------------------------------------------------------------------------
extern "C" void kernel_launch(void* const* d_in, const int* in_sizes, int n_in,
                              void* d_out, int out_size, void* d_ws, size_t ws_size,
                              hipStream_t stream) {
  (void)in_sizes; (void)n_in; (void)out_size; (void)ws_size;
  const float* head = (const float*)d_in[0];
  const float* tail = (const float*)d_in[1];
  // d_in[2] = lens (uniform L=16) -- unused
  const float* x = (const float*)d_in[3];
  const float* cmp = (const float*)d_in[4];
  const float* lab = (const float*)d_in[5];
  const unsigned char* lmask = (const unsigned char*)d_in[6];
  const float* w1 = (const float*)d_in[7];
  const float* b1 = (const float*)d_in[8];
  const float* w2 = (const float*)d_in[9];
  const float* b2 = (const float*)d_in[10];
  float* out = (float*)d_out;

  char* ws = (char*)d_ws;
  size_t off = 0;
  auto alloc = [&](size_t bytes) -> void* {
    void* p = ws + off; off += (bytes + 255) & ~(size_t)255; return p;
  };
  unsigned short* xt = (unsigned short*)alloc(4ull * 256 * 2048 * 2);
  unsigned short* w1t = (unsigned short*)alloc(256ull * 768 * 2);
  float* hrep = (float*)alloc(8192ull * 256 * 4);
  float* trep = (float*)alloc(8192ull * 256 * 4);
  unsigned short* featb = (unsigned short*)alloc(8192ull * 768 * 2);
  float* logits = (float*)alloc(8192ull * 2 * 4);
  float* refined = (float*)alloc(8192ull * 4);
  int* idxv = (int*)alloc(512 * 4);
  float* mvalv = (float*)alloc(512 * 4);
  int* cmaskv = (int*)alloc(512 * 4);
  int* njobs = (int*)alloc(256);
  int* jobs = (int*)alloc(8192 * 4);
  float* repm = (float*)alloc(512ull * 256 * 4);

  k_prep<<<560, 256, 0, stream>>>(x, w1, b2, xt, w1t, logits, njobs);
  k_gemm_rep<<<1024, 256, 0, stream>>>(head, tail, xt, hrep, trep);
  k_feat<<<2048, 256, 0, stream>>>(hrep, trep, featb);
  k_gemm_mlp<<<512, 256, 0, stream>>>(featb, w1t, b1, w2, logits);
  k_select<<<2, 256, 0, stream>>>(logits, idxv, mvalv, cmaskv, njobs, jobs);
  k_refine<<<256, 1024, 0, stream>>>(njobs, jobs, head, tail, x, w1, b1, w2, b2, refined);
  k_repm<<<512, 256, 0, stream>>>(idxv, mvalv, cmaskv, refined, trep, repm);
  k_merge<<<512, 256, 0, stream>>>(cmp, repm, x, out);
  k_loss<<<1, 1024, 0, stream>>>(logits, lab, lmask, out + 4ull * 2048 * 256);
}

// Round 3
// 322.154 us; speedup vs baseline: 1.0900x; 1.0900x over previous
//
#include <hip/hip_runtime.h>
#include <hip/hip_bf16.h>
#include <stdint.h>

// Problem constants (B=4, T=2048, D=256, M=128, L=16, P=2048)
#define TAU 0.35f   // bf16-path score uncertainty window for fp32 refinement

typedef __attribute__((ext_vector_type(8))) short bf16x8;
typedef __attribute__((ext_vector_type(4))) float f32x4;

__device__ __forceinline__ unsigned short f2bf(float f) {
  __bf16 h = (__bf16)f;
  return __builtin_bit_cast(unsigned short, h);
}
__device__ __forceinline__ float bf2f(unsigned short u) {
  unsigned int v = ((unsigned int)u) << 16;
  return __builtin_bit_cast(float, v);
}
__device__ __forceinline__ void async_copy16(const void* g, void* l) {
  __builtin_amdgcn_global_load_lds(
      (const __attribute__((address_space(1))) unsigned int*)g,
      (__attribute__((address_space(3))) unsigned int*)l, 16, 0, 0);
}

// ---------------------------------------------------------------------------
// K0: transpose+convert x -> xt[b][d][t] (bf16, K-contig); w1 -> w1t[n][k]
//     (bf16, K-contig); init logits with b2; zero njobs.
// ---------------------------------------------------------------------------
__global__ __launch_bounds__(256) void k_prep(
    const float* __restrict__ x, const float* __restrict__ w1,
    const float* __restrict__ b2,
    unsigned short* __restrict__ xt, unsigned short* __restrict__ w1t,
    float* __restrict__ logits, int* __restrict__ njobs) {
  __shared__ float tileS[64][65];
  int bx = blockIdx.x, tid = threadIdx.x;
  if (bx == 0 && tid == 0) *njobs = 0;
  if (bx < 64) {  // logits init: 16384 floats
    int i = bx * 256 + tid;
    logits[i] = b2[i & 1];
  }
  int j = tid & 63, i0 = tid >> 6;
  if (bx < 512) {                       // x tiles: b(4) * t-tiles(32) * d-tiles(4)
    int b = bx >> 7, t6 = (bx >> 2) & 31, d6 = bx & 3;
    const float* src = x + ((size_t)b * 2048 + (size_t)t6 * 64) * 256 + d6 * 64;
    for (int i = i0; i < 64; i += 4) tileS[i][j] = src[(size_t)i * 256 + j];
    __syncthreads();
    unsigned short* dst = xt + ((size_t)b * 256 + (size_t)d6 * 64) * 2048 + t6 * 64;
    for (int r = i0; r < 64; r += 4) dst[(size_t)r * 2048 + j] = f2bf(tileS[j][r]);
  } else {                              // w1 tiles: k-tiles(12) * n-tiles(4)
    int wt = bx - 512;
    int k6 = wt >> 2, n6 = wt & 3;
    const float* src = w1 + ((size_t)k6 * 64) * 256 + n6 * 64;
    for (int i = i0; i < 64; i += 4) tileS[i][j] = src[(size_t)i * 256 + j];
    __syncthreads();
    unsigned short* dst = w1t + ((size_t)n6 * 64) * 768 + k6 * 64;
    for (int r = i0; r < 64; r += 4) dst[(size_t)r * 768 + j] = f2bf(tileS[j][r]);
  }
}

// ---------------------------------------------------------------------------
// K1 v3: head_rep/tail_rep = [head;tail] @ x   (bf16 MFMA, fp32 out)
// A-READ-ONCE decomposition: one block owns one 64-row A tile and computes
// ALL 256 output cols (the B panel xt[b] is 1MB bf16, L2-resident, cheap to
// duplicate; the 134MB fp32 A is not). Grid = 256 = 1 block/CU, 512 threads
// (8 waves: 4 row-groups x 2 col-halves).
// Per K-chunk (BK=64):
//   - A: global->reg (fp32) issued EARLY, converted+ds_written LATE (after
//     the MFMA phase) so MFMA covers the load latency (T14 split).
//   - B: 4x global_load_lds per thread, XOR-swizzled chunk layout, dbuf.
//   - 128 MFMA/block/chunk (4x round-0's per-barrier work).
// LDS: A 2x8KB + B 2x32KB = 80KB -> 1 block/CU.
// ---------------------------------------------------------------------------
__global__ __launch_bounds__(512, 2) void k_gemm_rep(
    const float* __restrict__ head, const float* __restrict__ tail,
    const unsigned short* __restrict__ xt,
    float* __restrict__ hrep, float* __restrict__ trep) {
  __shared__ unsigned short As[2][4096];   // 64r x 64k bf16, frag-chunk layout
  __shared__ unsigned short Bs[2][16384];  // 256c x 64k bf16, chunk(col,k8) at
                                           // col*8 + (k8 ^ (col&7))
  int bx = blockIdx.x;
  int b = bx >> 6, mt = bx & 63;    // mt<32: head rows, else tail rows
  const float* Asrc = ((mt < 32) ? head : tail) +
                      ((size_t)(b * 2048 + (mt & 31) * 64)) * 2048;
  float* Crep = (mt < 32) ? hrep : trep;
  const unsigned short* Bsrc = xt + ((size_t)b * 256) * 2048;

  int tid = threadIdx.x, lane = tid & 63, w = tid >> 6;

  // ---- A staging: thread t handles row r=t>>3, k-octet q=t&7 (8 floats) ----
  int ar = tid >> 3, aq = tid & 7;
  const float* aptr = Asrc + (size_t)ar * 2048 + aq * 8;
  // frag-chunk layout (round-0-proven): chunk(row,ko) at
  //   (row>>4)*128 + (ko>>2)*64 + (ko&3)*16 + (row&15)
  int awi = ((ar >> 4) * 128 + (aq >> 2) * 64 + (aq & 3) * 16 + (ar & 15)) * 8;

  // ---- B staging: wave w stages cols w*32..w*32+31, 4 DMA/thread ----
  const unsigned short* bg[4];
  int bdst[4];
#pragma unroll
  for (int a = 0; a < 4; ++a) {
    int colofs = a * 8 + (lane >> 3);            // 0..31
    int col = w * 32 + colofs;
    int k8 = (lane & 7) ^ (colofs & 7);          // XOR swizzle (col&7==colofs&7)
    bg[a] = Bsrc + (size_t)col * 2048 + k8 * 8;
    bdst[a] = (w * 256 + a * 64 + lane) * 8;     // lane-linear LDS dest
  }

  // ---- fragment read indices ----
  int rt = w & 3;                  // row-group within 64-row tile
  int cg = (w >> 2) * 128;         // col-half base
  int sw0 = (lane >> 4) ^ (lane & 7);            // kh=0 swizzled slot
  int sw1 = (4 + (lane >> 4)) ^ (lane & 7);      // kh=1
  int colc[8];
#pragma unroll
  for (int ct = 0; ct < 8; ++ct) colc[ct] = (cg + ct * 16 + (lane & 15)) * 8;

  f32x4 acc[8];
#pragma unroll
  for (int ct = 0; ct < 8; ++ct) acc[ct] = (f32x4){0.f, 0.f, 0.f, 0.f};

  auto STAGEB = [&](int buf) {
#pragma unroll
    for (int a = 0; a < 4; ++a) { async_copy16(bg[a], &Bs[buf][bdst[a]]); bg[a] += 64; }
  };
  float4 av0, av1;
  auto LOADA = [&]() {             // issue only (no wait)
    const float4* ap = (const float4*)aptr;
    av0 = ap[0]; av1 = ap[1];
    aptr += 64;
  };
  auto WRITEA = [&](int buf) {     // convert + single ds_write_b128
    bf16x8 p;
    p[0] = (short)f2bf(av0.x); p[1] = (short)f2bf(av0.y);
    p[2] = (short)f2bf(av0.z); p[3] = (short)f2bf(av0.w);
    p[4] = (short)f2bf(av1.x); p[5] = (short)f2bf(av1.y);
    p[6] = (short)f2bf(av1.z); p[7] = (short)f2bf(av1.w);
    *(bf16x8*)&As[buf][awi] = p;
  };
  auto MMA = [&](int buf) {        // 16 MFMA per wave
    const unsigned short* A_ = As[buf];
    const unsigned short* B_ = Bs[buf];
    bf16x8 a0 = *(const bf16x8*)&A_[(rt * 128 + lane) * 8];
    bf16x8 a1 = *(const bf16x8*)&A_[(rt * 128 + 64 + lane) * 8];
#pragma unroll
    for (int ct = 0; ct < 8; ++ct) {
      bf16x8 b0 = *(const bf16x8*)&B_[(colc[ct] + sw0) * 8];
      acc[ct] = __builtin_amdgcn_mfma_f32_16x16x32_bf16(a0, b0, acc[ct], 0, 0, 0);
    }
#pragma unroll
    for (int ct = 0; ct < 8; ++ct) {
      bf16x8 b1 = *(const bf16x8*)&B_[(colc[ct] + sw1) * 8];
      acc[ct] = __builtin_amdgcn_mfma_f32_16x16x32_bf16(a1, b1, acc[ct], 0, 0, 0);
    }
  };

  // prologue: chunk 0 into buf0
  STAGEB(0);
  LOADA();
  WRITEA(0);
  __syncthreads();

  for (int it = 0; it < 32; ++it) {
    int cur = it & 1, nxt = cur ^ 1;
    if (it < 31) {
      STAGEB(nxt);     // B(it+1) DMA: issue early
      LOADA();         // A(it+1) global->reg: issue early
    }
    MMA(cur);          // MFMA phase covers the A-load latency
    if (it < 31) WRITEA(nxt);   // convert+write late (vmcnt wait lands here)
    __syncthreads();
  }

  // epilogue: C layout col=lane&15, row=(lane>>4)*4+i
  size_t prow = (size_t)b * 2048 + (size_t)(mt & 31) * 64 + rt * 16 + ((lane >> 4) << 2);
  int cb = cg + (lane & 15);
#pragma unroll
  for (int ct = 0; ct < 8; ++ct)
#pragma unroll
    for (int i = 0; i < 4; ++i)
      Crep[(prow + i) * 256 + cb + ct * 16] = acc[ct][i];
}

// ---------------------------------------------------------------------------
// K2pre: featbf[p][0:256]=h, [256:512]=t, [512:768]=h*t  (bf16)
// ---------------------------------------------------------------------------
__global__ __launch_bounds__(256) void k_feat(
    const float* __restrict__ hrep, const float* __restrict__ trep,
    unsigned short* __restrict__ featbf) {
  int gid = blockIdx.x * 256 + threadIdx.x;
  int p = gid >> 6, d0 = (gid & 63) * 4;
  float4 h4 = *(const float4*)&hrep[(size_t)p * 256 + d0];
  float4 t4 = *(const float4*)&trep[(size_t)p * 256 + d0];
  ushort4 a, bb, c;
  a.x = f2bf(h4.x); a.y = f2bf(h4.y); a.z = f2bf(h4.z); a.w = f2bf(h4.w);
  bb.x = f2bf(t4.x); bb.y = f2bf(t4.y); bb.z = f2bf(t4.z); bb.w = f2bf(t4.w);
  c.x = f2bf(h4.x * t4.x); c.y = f2bf(h4.y * t4.y);
  c.z = f2bf(h4.z * t4.z); c.w = f2bf(h4.w * t4.w);
  *(ushort4*)&featbf[(size_t)p * 768 + d0] = a;
  *(ushort4*)&featbf[(size_t)p * 768 + 256 + d0] = bb;
  *(ushort4*)&featbf[(size_t)p * 768 + 512 + d0] = c;
}

// ---------------------------------------------------------------------------
// K2: relu(feat @ w1 + b1) @ w2 + b2 -> logits (fused; atomicAdd partials).
// 64x64 tiles, BK=64, dbuf, all staging via global_load_lds (XOR swizzle).
// grid = 512 (2/CU). ntile = bx>>7 so siblings share XCD.
// ---------------------------------------------------------------------------
__global__ __launch_bounds__(256, 4) void k_gemm_mlp(
    const unsigned short* __restrict__ featb, const unsigned short* __restrict__ w1t,
    const float* __restrict__ b1, const float* __restrict__ w2,
    float* __restrict__ logits) {
  __shared__ unsigned short As[2][4096], Bs[2][4096];
  int bx = blockIdx.x;
  int ntile = bx >> 7;   // 0..3
  int mtile = bx & 127;  // 0..127
  int tid = threadIdx.x, lane = tid & 63, w = tid >> 6;

  const unsigned short* ag[2];
  const unsigned short* bgp[2];
  int dofs[2];
#pragma unroll
  for (int a = 0; a < 2; ++a) {
    int rowofs = a * 8 + (lane >> 3);
    int k8 = (lane & 7) ^ (rowofs & 7);
    ag[a] = featb + (size_t)(mtile * 64 + w * 16 + rowofs) * 768 + k8 * 8;
    bgp[a] = w1t + (size_t)(ntile * 64 + w * 16 + rowofs) * 768 + k8 * 8;
    dofs[a] = (w * 128 + a * 64 + lane) * 8;
  }
  int sw0 = (lane >> 4) ^ (lane & 7);
  int sw1 = (4 + (lane >> 4)) ^ (lane & 7);
  int arowc = (w * 16 + (lane & 15)) * 8;
  int colc[4];
#pragma unroll
  for (int ct = 0; ct < 4; ++ct) colc[ct] = (ct * 16 + (lane & 15)) * 8;

  f32x4 acc[4];
#pragma unroll
  for (int ct = 0; ct < 4; ++ct) acc[ct] = (f32x4){0.f, 0.f, 0.f, 0.f};

#pragma unroll
  for (int a = 0; a < 2; ++a) {
    async_copy16(ag[a], &As[0][dofs[a]]); ag[a] += 64;
    async_copy16(bgp[a], &Bs[0][dofs[a]]); bgp[a] += 64;
  }
  __syncthreads();

  for (int it = 0; it < 12; ++it) {
    int cur = it & 1, nxt = cur ^ 1;
    if (it < 11) {
#pragma unroll
      for (int a = 0; a < 2; ++a) {
        async_copy16(ag[a], &As[nxt][dofs[a]]); ag[a] += 64;
        async_copy16(bgp[a], &Bs[nxt][dofs[a]]); bgp[a] += 64;
      }
    }
    const unsigned short* A_ = As[cur];
    const unsigned short* B_ = Bs[cur];
    bf16x8 a0 = *(const bf16x8*)&A_[(arowc + sw0) * 8];
    bf16x8 a1 = *(const bf16x8*)&A_[(arowc + sw1) * 8];
#pragma unroll
    for (int ct = 0; ct < 4; ++ct) {
      bf16x8 b0 = *(const bf16x8*)&B_[(colc[ct] + sw0) * 8];
      acc[ct] = __builtin_amdgcn_mfma_f32_16x16x32_bf16(a0, b0, acc[ct], 0, 0, 0);
    }
#pragma unroll
    for (int ct = 0; ct < 4; ++ct) {
      bf16x8 b1 = *(const bf16x8*)&B_[(colc[ct] + sw1) * 8];
      acc[ct] = __builtin_amdgcn_mfma_f32_16x16x32_bf16(a1, b1, acc[ct], 0, 0, 0);
    }
    __syncthreads();
  }

  // epilogue: relu(+b1), dot with w2 cols, reduce over the 16-lane col group
  float bv[4], w20[4], w21[4];
#pragma unroll
  for (int ct = 0; ct < 4; ++ct) {
    int col = ntile * 64 + ct * 16 + (lane & 15);
    bv[ct] = b1[col]; w20[ct] = w2[col * 2]; w21[ct] = w2[col * 2 + 1];
  }
#pragma unroll
  for (int i = 0; i < 4; ++i) {
    float s0 = 0.f, s1 = 0.f;
#pragma unroll
    for (int ct = 0; ct < 4; ++ct) {
      float r = fmaxf(acc[ct][i] + bv[ct], 0.f);
      s0 += r * w20[ct]; s1 += r * w21[ct];
    }
#pragma unroll
    for (int off = 1; off < 16; off <<= 1) {
      s0 += __shfl_xor(s0, off); s1 += __shfl_xor(s1, off);
    }
    if ((lane & 15) == 0) {
      int row = mtile * 64 + w * 16 + ((lane >> 4) << 2) + i;
      atomicAdd(&logits[row * 2], s0);
      atomicAdd(&logits[row * 2 + 1], s1);
    }
  }
}

// ---------------------------------------------------------------------------
// K3b: per-mention top-1 + uncertainty set; emit refine jobs
// ---------------------------------------------------------------------------
__global__ void k_select(const float* __restrict__ logits, int* __restrict__ idxv,
                         float* __restrict__ mval, int* __restrict__ cmask,
                         int* __restrict__ njobs, int* __restrict__ jobs) {
  int q = blockIdx.x * 256 + threadIdx.x;
  if (q >= 512) return;
  int base = q * 16;
  float s[16];
#pragma unroll
  for (int i = 0; i < 16; ++i) s[i] = logits[(size_t)(base + i) * 2 + 1];
  float best = s[0]; int bi = 0;
#pragma unroll
  for (int i = 1; i < 16; ++i) if (s[i] > best) { best = s[i]; bi = i; }
  int mask = 0, cnt = 0;
#pragma unroll
  for (int i = 0; i < 16; ++i) if (s[i] > best - TAU) { mask |= 1 << i; ++cnt; }
  idxv[q] = bi; mval[q] = best;
  if (cnt > 1) {
    cmask[q] = mask;
    for (int i = 0; i < 16; ++i)
      if ((mask >> i) & 1) { int j = atomicAdd(njobs, 1); jobs[j] = base + i; }
  } else cmask[q] = 0;
}

// ---------------------------------------------------------------------------
// K3c: fp32 exact score recompute for uncertain candidate pairs
// ---------------------------------------------------------------------------
__global__ __launch_bounds__(1024) void k_refine(
    const int* __restrict__ njobs, const int* __restrict__ jobs,
    const float* __restrict__ head, const float* __restrict__ tail,
    const float* __restrict__ x, const float* __restrict__ w1,
    const float* __restrict__ b1, const float* __restrict__ w2,
    const float* __restrict__ b2, float* __restrict__ refined) {
  __shared__ float hrow[2048], trow[2048], feat[768], red[1024], red2[1024];
  int tid = threadIdx.x, seg = tid >> 8, d = tid & 255;
  int nj = *njobs;
  for (int job = blockIdx.x; job < nj; job += gridDim.x) {
    int code = jobs[job];
    int b = code >> 11, p = code & 2047;
    if (tid < 512)
      *(float4*)&hrow[tid * 4] = *(const float4*)&head[((size_t)(b * 2048 + p)) * 2048 + tid * 4];
    else {
      int u = tid - 512;
      *(float4*)&trow[u * 4] = *(const float4*)&tail[((size_t)(b * 2048 + p)) * 2048 + u * 4];
    }
    __syncthreads();
    float hr = 0.f, tr = 0.f;
    const float* xb = x + ((size_t)b * 2048) * 256 + d;
#pragma unroll 8
    for (int t = seg * 512; t < seg * 512 + 512; ++t) {
      float xv = xb[(size_t)t * 256];
      hr += hrow[t] * xv; tr += trow[t] * xv;
    }
    red[tid] = hr; red2[tid] = tr;
    __syncthreads();
    if (seg == 0) {
      float fh = red[d] + red[256 + d] + red[512 + d] + red[768 + d];
      float ft = red2[d] + red2[256 + d] + red2[512 + d] + red2[768 + d];
      feat[d] = fh; feat[256 + d] = ft; feat[512 + d] = fh * ft;
    }
    __syncthreads();
    float hp = 0.f;
    for (int ii = seg * 192; ii < seg * 192 + 192; ++ii) hp += feat[ii] * w1[(size_t)ii * 256 + d];
    red[tid] = hp;
    __syncthreads();
    if (seg == 0) {
      float hj = b1[d] + red[d] + red[256 + d] + red[512 + d] + red[768 + d];
      hj = fmaxf(hj, 0.f);
      red2[d] = hj * w2[d * 2 + 1];
    }
    __syncthreads();
    for (int s = 128; s > 0; s >>= 1) {
      if (tid < s) red2[tid] += red2[tid + s];
      __syncthreads();
    }
    if (tid == 0) refined[code] = red2[0] + b2[1];
    __syncthreads();
  }
}

// ---------------------------------------------------------------------------
// K4a: rep_m[q][d] = tail_rep[q*16+argmax][d] * max_val
// ---------------------------------------------------------------------------
__global__ __launch_bounds__(256) void k_repm(
    const int* __restrict__ idxv, const float* __restrict__ mval,
    const int* __restrict__ cmask, const float* __restrict__ refined,
    const float* __restrict__ trep, float* __restrict__ repm) {
  int q = blockIdx.x, d = threadIdx.x;
  int mask = cmask[q]; int bi; float v;
  if (mask) {
    bi = -1; v = -1e30f;
    for (int i = 0; i < 16; ++i)
      if ((mask >> i) & 1) { float s = refined[q * 16 + i]; if (s > v) { v = s; bi = i; } }
  } else { bi = idxv[q]; v = mval[q]; }
  repm[(size_t)q * 256 + d] = trep[((size_t)q * 16 + bi) * 256 + d] * v;
}

// ---------------------------------------------------------------------------
// K4b: out[b][t][d] = x + sum_m cmp[b][m][t] * rep_m[b][m][d]  (512 blocks)
// ---------------------------------------------------------------------------
__global__ __launch_bounds__(256) void k_merge(
    const float* __restrict__ cmp, const float* __restrict__ repm,
    const float* __restrict__ x, float* __restrict__ out) {
  __shared__ float cl[128 * 16];
  int bx = blockIdx.x, b = bx >> 7, t0 = (bx & 127) * 16;
  int tid = threadIdx.x;
#pragma unroll
  for (int it = 0; it < 2; ++it) {
    int f = it * 256 + tid;
    int row = f >> 2, c4 = (f & 3) * 4;
    *(float4*)&cl[row * 16 + c4] =
        *(const float4*)&cmp[((size_t)(b * 128 + row)) * 2048 + t0 + c4];
  }
  __syncthreads();
  float acc[16];
#pragma unroll
  for (int i = 0; i < 16; ++i) acc[i] = 0.f;
  int d = tid;
  for (int m = 0; m < 128; ++m) {
    float rv = repm[(size_t)(b * 128 + m) * 256 + d];
    const float4* c4p = (const float4*)&cl[m * 16];
#pragma unroll
    for (int jj = 0; jj < 4; ++jj) {
      float4 c = c4p[jj];
      acc[jj * 4] += c.x * rv; acc[jj * 4 + 1] += c.y * rv;
      acc[jj * 4 + 2] += c.z * rv; acc[jj * 4 + 3] += c.w * rv;
    }
  }
  const float* xb = x + ((size_t)(b * 2048 + t0)) * 256 + d;
  float* ob = out + ((size_t)(b * 2048 + t0)) * 256 + d;
#pragma unroll
  for (int tt = 0; tt < 16; ++tt) ob[(size_t)tt * 256] = xb[(size_t)tt * 256] + acc[tt];
}

// ---------------------------------------------------------------------------
// K5: masked KLDiv mean loss (single block)
// ---------------------------------------------------------------------------
__global__ __launch_bounds__(1024) void k_loss(
    const float* __restrict__ logits, const float* __restrict__ lab,
    const unsigned char* __restrict__ mask, float* __restrict__ out_loss) {
  __shared__ float rs[1024], rc[1024];
  int tid = threadIdx.x;
  float sum = 0.f, cnt = 0.f;
  for (int p = tid; p < 8192; p += 1024) {
    float l0 = logits[(size_t)p * 2], l1 = logits[(size_t)p * 2 + 1];
    float a0 = lab[(size_t)p * 2], a1 = lab[(size_t)p * 2 + 1];
    float mx = fmaxf(l0, l1);
    float lse = mx + logf(expf(l0 - mx) + expf(l1 - mx));
    float pw = 0.f;
    if (a0 > 0.f) pw += a0 * logf(fmaxf(a0, 1e-38f));
    if (a1 > 0.f) pw += a1 * logf(fmaxf(a1, 1e-38f));
    pw -= a0 * (l0 - lse) + a1 * (l1 - lse);
    if (mask[p]) { sum += pw; cnt += 1.f; }
  }
  rs[tid] = sum; rc[tid] = cnt;
  __syncthreads();
  for (int s = 512; s > 0; s >>= 1) {
    if (tid < s) { rs[tid] += rs[tid + s]; rc[tid] += rc[tid + s]; }
    __syncthreads();
  }
  if (tid == 0) *out_loss = rs[0] / (rc[0] * 2.0f);
}

// ---------------------------------------------------------------------------
extern "C" void kernel_launch(void* const* d_in, const int* in_sizes, int n_in,
                              void* d_out, int out_size, void* d_ws, size_t ws_size,
                              hipStream_t stream) {
  (void)in_sizes; (void)n_in; (void)out_size; (void)ws_size;
  const float* head = (const float*)d_in[0];
  const float* tail = (const float*)d_in[1];
  // d_in[2] = lens (uniform L=16) -- unused
  const float* x = (const float*)d_in[3];
  const float* cmp = (const float*)d_in[4];
  const float* lab = (const float*)d_in[5];
  const unsigned char* lmask = (const unsigned char*)d_in[6];
  const float* w1 = (const float*)d_in[7];
  const float* b1 = (const float*)d_in[8];
  const float* w2 = (const float*)d_in[9];
  const float* b2 = (const float*)d_in[10];
  float* out = (float*)d_out;

  char* ws = (char*)d_ws;
  size_t off = 0;
  auto alloc = [&](size_t bytes) -> void* {
    void* p = ws + off; off += (bytes + 255) & ~(size_t)255; return p;
  };
  unsigned short* xt = (unsigned short*)alloc(4ull * 256 * 2048 * 2);
  unsigned short* w1t = (unsigned short*)alloc(256ull * 768 * 2);
  float* hrep = (float*)alloc(8192ull * 256 * 4);
  float* trep = (float*)alloc(8192ull * 256 * 4);
  unsigned short* featb = (unsigned short*)alloc(8192ull * 768 * 2);
  float* logits = (float*)alloc(8192ull * 2 * 4);
  float* refined = (float*)alloc(8192ull * 4);
  int* idxv = (int*)alloc(512 * 4);
  float* mvalv = (float*)alloc(512 * 4);
  int* cmaskv = (int*)alloc(512 * 4);
  int* njobs = (int*)alloc(256);
  int* jobs = (int*)alloc(8192 * 4);
  float* repm = (float*)alloc(512ull * 256 * 4);

  k_prep<<<560, 256, 0, stream>>>(x, w1, b2, xt, w1t, logits, njobs);
  k_gemm_rep<<<256, 512, 0, stream>>>(head, tail, xt, hrep, trep);
  k_feat<<<2048, 256, 0, stream>>>(hrep, trep, featb);
  k_gemm_mlp<<<512, 256, 0, stream>>>(featb, w1t, b1, w2, logits);
  k_select<<<2, 256, 0, stream>>>(logits, idxv, mvalv, cmaskv, njobs, jobs);
  k_refine<<<256, 1024, 0, stream>>>(njobs, jobs, head, tail, x, w1, b1, w2, b2, refined);
  k_repm<<<512, 256, 0, stream>>>(idxv, mvalv, cmaskv, refined, trep, repm);
  k_merge<<<512, 256, 0, stream>>>(cmp, repm, x, out);
  k_loss<<<1, 1024, 0, stream>>>(logits, lab, lmask, out + 4ull * 2048 * 256);
}

// Round 4
// 315.591 us; speedup vs baseline: 1.1127x; 1.0208x over previous
//
#include <hip/hip_runtime.h>
#include <hip/hip_bf16.h>
#include <stdint.h>

// Problem constants (B=4, T=2048, D=256, M=128, L=16, P=2048)
#define TAU 0.35f   // bf16-path score uncertainty window for fp32 refinement

typedef __attribute__((ext_vector_type(8))) short bf16x8;
typedef __attribute__((ext_vector_type(4))) float f32x4;

__device__ __forceinline__ unsigned short f2bf(float f) {
  __bf16 h = (__bf16)f;
  return __builtin_bit_cast(unsigned short, h);
}
__device__ __forceinline__ float bf2f(unsigned short u) {
  unsigned int v = ((unsigned int)u) << 16;
  return __builtin_bit_cast(float, v);
}
__device__ __forceinline__ void async_copy16(const void* g, void* l) {
  __builtin_amdgcn_global_load_lds(
      (const __attribute__((address_space(1))) unsigned int*)g,
      (__attribute__((address_space(3))) unsigned int*)l, 16, 0, 0);
}

// ---------------------------------------------------------------------------
// K0: x -> xt2[b][kc][k8][d][8] (bf16, k-slice-major: t = kc*64 + k8*8 + ke).
//     This layout makes K1's B staging a LINEAR copy (coalesced global,
//     lane-linear LDS dest) and all fragment ds_reads bank-minimal with NO
//     swizzle. Also: w1 -> w1t[n][k] (unchanged); logits init; njobs zero.
// grid = 304: bx<256 x-part (b=bx>>6, kc=(bx>>1)&31, dh=bx&1);
//             256<=bx<304 w1-part; logits overlay on bx<64.
// ---------------------------------------------------------------------------
__global__ __launch_bounds__(256) void k_prep(
    const float* __restrict__ x, const float* __restrict__ w1,
    const float* __restrict__ b2,
    unsigned short* __restrict__ xt, unsigned short* __restrict__ w1t,
    float* __restrict__ logits, int* __restrict__ njobs) {
  __shared__ float tileS[64][65];
  __shared__ float tx[64][132];
  int bx = blockIdx.x, tid = threadIdx.x;
  if (bx == 0 && tid == 0) *njobs = 0;
  if (bx < 64) {  // logits init: 16384 floats
    int i = bx * 256 + tid;
    logits[i] = b2[i & 1];
  }
  if (bx < 256) {  // x-part: 64 t-rows x 128 d-cols per block
    int b = bx >> 6, kc = (bx >> 1) & 31, dh = bx & 1;
    const float* src = x + ((size_t)b * 2048 + (size_t)kc * 64) * 256 + dh * 128;
#pragma unroll
    for (int p = 0; p < 8; ++p) {
      int idx = p * 256 + tid;
      int row = idx >> 5, f4 = idx & 31;   // row 0..63, f4 0..31 (128 floats)
      *(float4*)&tx[row][f4 * 4] = *(const float4*)&src[(size_t)row * 256 + f4 * 4];
    }
    __syncthreads();
    unsigned short* dst = xt + ((size_t)(b * 32 + kc)) * 16384 + dh * 1024;
#pragma unroll
    for (int p = 0; p < 4; ++p) {
      int idx = p * 256 + tid;
      int d0 = idx & 127, k8 = idx >> 7;   // d0 0..127, k8 0..7
      bf16x8 v;
#pragma unroll
      for (int j = 0; j < 8; ++j) v[j] = (short)f2bf(tx[k8 * 8 + j][d0]);
      *(bf16x8*)&dst[(size_t)k8 * 2048 + d0 * 8] = v;
    }
  } else {  // w1 tiles: k-tiles(12) * n-tiles(4)  (unchanged layout)
    int wt = bx - 256;
    int k6 = wt >> 2, n6 = wt & 3;
    int j = tid & 63, i0 = tid >> 6;
    const float* src = w1 + ((size_t)k6 * 64) * 256 + n6 * 64;
    for (int i = i0; i < 64; i += 4) tileS[i][j] = src[(size_t)i * 256 + j];
    __syncthreads();
    unsigned short* dst = w1t + ((size_t)n6 * 64) * 768 + k6 * 64;
    for (int r = i0; r < 64; r += 4) dst[(size_t)r * 768 + j] = f2bf(tileS[j][r]);
  }
}

// ---------------------------------------------------------------------------
// K1 v4: head_rep/tail_rep = [head;tail] @ x   (bf16 MFMA, fp32 out)
// Fetch-once + 2 blocks/CU:
//  - block = 32 A-rows x ALL 256 cols (A read exactly once; B panel 1MB/batch
//    is L2-resident and shared across blocks). grid = 512 = 2 blocks/CU.
//  - LDS 72KB/block: B dbuf 2x32KB ([k8][col][8], linear DMA, no swizzle),
//    A dbuf 2x4KB ([k8][row][8], reg-staged fp32->bf16).
//  - BK=64, 32 iters; 8 waves = 2 rowgroups x 4 colgroups; 8 MFMA/wave/iter.
//  - All fragment ds_reads are 16-lane-contiguous 256B -> bank-minimal.
// Two blocks/CU interleave barrier drains (the r3 killer).
// ---------------------------------------------------------------------------
__global__ __launch_bounds__(512, 4) void k_gemm_rep(
    const float* __restrict__ head, const float* __restrict__ tail,
    const unsigned short* __restrict__ xt,
    float* __restrict__ hrep, float* __restrict__ trep) {
  __shared__ unsigned short As[2][2048];   // [k8 0..7][row 0..31][8]
  __shared__ unsigned short Bs[2][16384];  // [k8 0..7][col 0..255][8]
  int bx = blockIdx.x;
  int b = bx >> 7, mt = bx & 127;   // mt<64: head rowtile, else tail
  const float* Asrc = ((mt < 64) ? head : tail) +
                      ((size_t)(b * 2048 + (mt & 63) * 32)) * 2048;
  float* Crep = (mt < 64) ? hrep : trep;
  const unsigned short* Bsrc = xt + (size_t)b * 524288;

  int tid = threadIdx.x, lane = tid & 63, w = tid >> 6;
  int rg = w & 1, cg = w >> 1;
  int l4 = lane >> 4, l15 = lane & 15;

  // ---- A staging (tid<256): row=tid>>3, k8=tid&7; 2x float4 = one k-octet ---
  int arow = tid >> 3, ak8 = tid & 7;
  const float* aptr = Asrc + (size_t)arow * 2048 + ak8 * 8;
  int awi = (ak8 * 32 + arow) * 8;

  // ---- B staging: linear copy, 4 DMA/thread ----
  const unsigned short* bg = Bsrc + tid * 8;

  // ---- fragment read offsets ----
  int aoff[2];
  int boff[2][4];
#pragma unroll
  for (int kh = 0; kh < 2; ++kh) {
    aoff[kh] = ((kh * 4 + l4) * 32 + rg * 16 + l15) * 8;
#pragma unroll
    for (int ct = 0; ct < 4; ++ct)
      boff[kh][ct] = ((kh * 4 + l4) * 256 + cg * 64 + ct * 16 + l15) * 8;
  }

  f32x4 acc[4];
#pragma unroll
  for (int ct = 0; ct < 4; ++ct) acc[ct] = (f32x4){0.f, 0.f, 0.f, 0.f};

  float4 av0, av1;
  auto STAGEB = [&](int buf) {
#pragma unroll
    for (int a = 0; a < 4; ++a)
      async_copy16(bg + (size_t)a * 4096, &Bs[buf][(tid + a * 512) * 8]);
    bg += 16384;
  };
  auto LOADA = [&]() {
    const float4* ap = (const float4*)aptr;
    av0 = ap[0]; av1 = ap[1];
    aptr += 64;
  };
  auto WRITEA = [&](int buf) {
    bf16x8 p;
    p[0] = (short)f2bf(av0.x); p[1] = (short)f2bf(av0.y);
    p[2] = (short)f2bf(av0.z); p[3] = (short)f2bf(av0.w);
    p[4] = (short)f2bf(av1.x); p[5] = (short)f2bf(av1.y);
    p[6] = (short)f2bf(av1.z); p[7] = (short)f2bf(av1.w);
    *(bf16x8*)&As[buf][awi] = p;
  };
  auto MMA = [&](int buf) {
    const unsigned short* A_ = As[buf];
    const unsigned short* B_ = Bs[buf];
#pragma unroll
    for (int kh = 0; kh < 2; ++kh) {
      bf16x8 a0 = *(const bf16x8*)&A_[aoff[kh]];
#pragma unroll
      for (int ct = 0; ct < 4; ++ct) {
        bf16x8 bb = *(const bf16x8*)&B_[boff[kh][ct]];
        acc[ct] = __builtin_amdgcn_mfma_f32_16x16x32_bf16(a0, bb, acc[ct], 0, 0, 0);
      }
    }
  };

  // prologue: chunk 0
  STAGEB(0);
  if (tid < 256) { LOADA(); WRITEA(0); }
  __syncthreads();

  for (int it = 0; it < 32; ++it) {
    int cur = it & 1, nxt = cur ^ 1;
    if (it < 31) {
      STAGEB(nxt);                 // B(it+1) DMA: issue early
      if (tid < 256) LOADA();      // A(it+1) global->reg: issue early
    }
    MMA(cur);                      // MFMA covers the A-load latency
    if (it < 31 && tid < 256) WRITEA(nxt);  // convert+write late
    __syncthreads();
  }

  // epilogue: C layout col=lane&15, row=(lane>>4)*4+i
  size_t prow = (size_t)b * 2048 + (size_t)(mt & 63) * 32 + rg * 16 + (l4 << 2);
  int cb = cg * 64 + l15;
#pragma unroll
  for (int ct = 0; ct < 4; ++ct)
#pragma unroll
    for (int i = 0; i < 4; ++i)
      Crep[(prow + i) * 256 + cb + ct * 16] = acc[ct][i];
}

// ---------------------------------------------------------------------------
// K2pre: featbf[p][0:256]=h, [256:512]=t, [512:768]=h*t  (bf16)
// ---------------------------------------------------------------------------
__global__ __launch_bounds__(256) void k_feat(
    const float* __restrict__ hrep, const float* __restrict__ trep,
    unsigned short* __restrict__ featbf) {
  int gid = blockIdx.x * 256 + threadIdx.x;
  int p = gid >> 6, d0 = (gid & 63) * 4;
  float4 h4 = *(const float4*)&hrep[(size_t)p * 256 + d0];
  float4 t4 = *(const float4*)&trep[(size_t)p * 256 + d0];
  ushort4 a, bb, c;
  a.x = f2bf(h4.x); a.y = f2bf(h4.y); a.z = f2bf(h4.z); a.w = f2bf(h4.w);
  bb.x = f2bf(t4.x); bb.y = f2bf(t4.y); bb.z = f2bf(t4.z); bb.w = f2bf(t4.w);
  c.x = f2bf(h4.x * t4.x); c.y = f2bf(h4.y * t4.y);
  c.z = f2bf(h4.z * t4.z); c.w = f2bf(h4.w * t4.w);
  *(ushort4*)&featbf[(size_t)p * 768 + d0] = a;
  *(ushort4*)&featbf[(size_t)p * 768 + 256 + d0] = bb;
  *(ushort4*)&featbf[(size_t)p * 768 + 512 + d0] = c;
}

// ---------------------------------------------------------------------------
// K2: relu(feat @ w1 + b1) @ w2 + b2 -> logits (fused; atomicAdd partials).
// 64x64 tiles, BK=64, dbuf, all staging via global_load_lds (XOR swizzle).
// grid = 512 (2/CU). ntile = bx>>7 so siblings share XCD.
// ---------------------------------------------------------------------------
__global__ __launch_bounds__(256, 4) void k_gemm_mlp(
    const unsigned short* __restrict__ featb, const unsigned short* __restrict__ w1t,
    const float* __restrict__ b1, const float* __restrict__ w2,
    float* __restrict__ logits) {
  __shared__ unsigned short As[2][4096], Bs[2][4096];
  int bx = blockIdx.x;
  int ntile = bx >> 7;   // 0..3
  int mtile = bx & 127;  // 0..127
  int tid = threadIdx.x, lane = tid & 63, w = tid >> 6;

  const unsigned short* ag[2];
  const unsigned short* bgp[2];
  int dofs[2];
#pragma unroll
  for (int a = 0; a < 2; ++a) {
    int rowofs = a * 8 + (lane >> 3);
    int k8 = (lane & 7) ^ (rowofs & 7);
    ag[a] = featb + (size_t)(mtile * 64 + w * 16 + rowofs) * 768 + k8 * 8;
    bgp[a] = w1t + (size_t)(ntile * 64 + w * 16 + rowofs) * 768 + k8 * 8;
    dofs[a] = (w * 128 + a * 64 + lane) * 8;
  }
  int sw0 = (lane >> 4) ^ (lane & 7);
  int sw1 = (4 + (lane >> 4)) ^ (lane & 7);
  int arowc = (w * 16 + (lane & 15)) * 8;
  int colc[4];
#pragma unroll
  for (int ct = 0; ct < 4; ++ct) colc[ct] = (ct * 16 + (lane & 15)) * 8;

  f32x4 acc[4];
#pragma unroll
  for (int ct = 0; ct < 4; ++ct) acc[ct] = (f32x4){0.f, 0.f, 0.f, 0.f};

#pragma unroll
  for (int a = 0; a < 2; ++a) {
    async_copy16(ag[a], &As[0][dofs[a]]); ag[a] += 64;
    async_copy16(bgp[a], &Bs[0][dofs[a]]); bgp[a] += 64;
  }
  __syncthreads();

  for (int it = 0; it < 12; ++it) {
    int cur = it & 1, nxt = cur ^ 1;
    if (it < 11) {
#pragma unroll
      for (int a = 0; a < 2; ++a) {
        async_copy16(ag[a], &As[nxt][dofs[a]]); ag[a] += 64;
        async_copy16(bgp[a], &Bs[nxt][dofs[a]]); bgp[a] += 64;
      }
    }
    const unsigned short* A_ = As[cur];
    const unsigned short* B_ = Bs[cur];
    bf16x8 a0 = *(const bf16x8*)&A_[(arowc + sw0) * 8];
    bf16x8 a1 = *(const bf16x8*)&A_[(arowc + sw1) * 8];
#pragma unroll
    for (int ct = 0; ct < 4; ++ct) {
      bf16x8 b0 = *(const bf16x8*)&B_[(colc[ct] + sw0) * 8];
      acc[ct] = __builtin_amdgcn_mfma_f32_16x16x32_bf16(a0, b0, acc[ct], 0, 0, 0);
    }
#pragma unroll
    for (int ct = 0; ct < 4; ++ct) {
      bf16x8 b1 = *(const bf16x8*)&B_[(colc[ct] + sw1) * 8];
      acc[ct] = __builtin_amdgcn_mfma_f32_16x16x32_bf16(a1, b1, acc[ct], 0, 0, 0);
    }
    __syncthreads();
  }

  // epilogue: relu(+b1), dot with w2 cols, reduce over the 16-lane col group
  float bv[4], w20[4], w21[4];
#pragma unroll
  for (int ct = 0; ct < 4; ++ct) {
    int col = ntile * 64 + ct * 16 + (lane & 15);
    bv[ct] = b1[col]; w20[ct] = w2[col * 2]; w21[ct] = w2[col * 2 + 1];
  }
#pragma unroll
  for (int i = 0; i < 4; ++i) {
    float s0 = 0.f, s1 = 0.f;
#pragma unroll
    for (int ct = 0; ct < 4; ++ct) {
      float r = fmaxf(acc[ct][i] + bv[ct], 0.f);
      s0 += r * w20[ct]; s1 += r * w21[ct];
    }
#pragma unroll
    for (int off = 1; off < 16; off <<= 1) {
      s0 += __shfl_xor(s0, off); s1 += __shfl_xor(s1, off);
    }
    if ((lane & 15) == 0) {
      int row = mtile * 64 + w * 16 + ((lane >> 4) << 2) + i;
      atomicAdd(&logits[row * 2], s0);
      atomicAdd(&logits[row * 2 + 1], s1);
    }
  }
}

// ---------------------------------------------------------------------------
// K3b: per-mention top-1 + uncertainty set; emit refine jobs
// ---------------------------------------------------------------------------
__global__ void k_select(const float* __restrict__ logits, int* __restrict__ idxv,
                         float* __restrict__ mval, int* __restrict__ cmask,
                         int* __restrict__ njobs, int* __restrict__ jobs) {
  int q = blockIdx.x * 256 + threadIdx.x;
  if (q >= 512) return;
  int base = q * 16;
  float s[16];
#pragma unroll
  for (int i = 0; i < 16; ++i) s[i] = logits[(size_t)(base + i) * 2 + 1];
  float best = s[0]; int bi = 0;
#pragma unroll
  for (int i = 1; i < 16; ++i) if (s[i] > best) { best = s[i]; bi = i; }
  int mask = 0, cnt = 0;
#pragma unroll
  for (int i = 0; i < 16; ++i) if (s[i] > best - TAU) { mask |= 1 << i; ++cnt; }
  idxv[q] = bi; mval[q] = best;
  if (cnt > 1) {
    cmask[q] = mask;
    for (int i = 0; i < 16; ++i)
      if ((mask >> i) & 1) { int j = atomicAdd(njobs, 1); jobs[j] = base + i; }
  } else cmask[q] = 0;
}

// ---------------------------------------------------------------------------
// K3c: fp32 exact score recompute for uncertain candidate pairs
// ---------------------------------------------------------------------------
__global__ __launch_bounds__(1024) void k_refine(
    const int* __restrict__ njobs, const int* __restrict__ jobs,
    const float* __restrict__ head, const float* __restrict__ tail,
    const float* __restrict__ x, const float* __restrict__ w1,
    const float* __restrict__ b1, const float* __restrict__ w2,
    const float* __restrict__ b2, float* __restrict__ refined) {
  __shared__ float hrow[2048], trow[2048], feat[768], red[1024], red2[1024];
  int tid = threadIdx.x, seg = tid >> 8, d = tid & 255;
  int nj = *njobs;
  for (int job = blockIdx.x; job < nj; job += gridDim.x) {
    int code = jobs[job];
    int b = code >> 11, p = code & 2047;
    if (tid < 512)
      *(float4*)&hrow[tid * 4] = *(const float4*)&head[((size_t)(b * 2048 + p)) * 2048 + tid * 4];
    else {
      int u = tid - 512;
      *(float4*)&trow[u * 4] = *(const float4*)&tail[((size_t)(b * 2048 + p)) * 2048 + u * 4];
    }
    __syncthreads();
    float hr = 0.f, tr = 0.f;
    const float* xb = x + ((size_t)b * 2048) * 256 + d;
#pragma unroll 8
    for (int t = seg * 512; t < seg * 512 + 512; ++t) {
      float xv = xb[(size_t)t * 256];
      hr += hrow[t] * xv; tr += trow[t] * xv;
    }
    red[tid] = hr; red2[tid] = tr;
    __syncthreads();
    if (seg == 0) {
      float fh = red[d] + red[256 + d] + red[512 + d] + red[768 + d];
      float ft = red2[d] + red2[256 + d] + red2[512 + d] + red2[768 + d];
      feat[d] = fh; feat[256 + d] = ft; feat[512 + d] = fh * ft;
    }
    __syncthreads();
    float hp = 0.f;
    for (int ii = seg * 192; ii < seg * 192 + 192; ++ii) hp += feat[ii] * w1[(size_t)ii * 256 + d];
    red[tid] = hp;
    __syncthreads();
    if (seg == 0) {
      float hj = b1[d] + red[d] + red[256 + d] + red[512 + d] + red[768 + d];
      hj = fmaxf(hj, 0.f);
      red2[d] = hj * w2[d * 2 + 1];
    }
    __syncthreads();
    for (int s = 128; s > 0; s >>= 1) {
      if (tid < s) red2[tid] += red2[tid + s];
      __syncthreads();
    }
    if (tid == 0) refined[code] = red2[0] + b2[1];
    __syncthreads();
  }
}

// ---------------------------------------------------------------------------
// K4a: rep_m[q][d] = tail_rep[q*16+argmax][d] * max_val
// ---------------------------------------------------------------------------
__global__ __launch_bounds__(256) void k_repm(
    const int* __restrict__ idxv, const float* __restrict__ mval,
    const int* __restrict__ cmask, const float* __restrict__ refined,
    const float* __restrict__ trep, float* __restrict__ repm) {
  int q = blockIdx.x, d = threadIdx.x;
  int mask = cmask[q]; int bi; float v;
  if (mask) {
    bi = -1; v = -1e30f;
    for (int i = 0; i < 16; ++i)
      if ((mask >> i) & 1) { float s = refined[q * 16 + i]; if (s > v) { v = s; bi = i; } }
  } else { bi = idxv[q]; v = mval[q]; }
  repm[(size_t)q * 256 + d] = trep[((size_t)q * 16 + bi) * 256 + d] * v;
}

// ---------------------------------------------------------------------------
// K4b: out[b][t][d] = x + sum_m cmp[b][m][t] * rep_m[b][m][d]  (512 blocks)
// ---------------------------------------------------------------------------
__global__ __launch_bounds__(256) void k_merge(
    const float* __restrict__ cmp, const float* __restrict__ repm,
    const float* __restrict__ x, float* __restrict__ out) {
  __shared__ float cl[128 * 16];
  int bx = blockIdx.x, b = bx >> 7, t0 = (bx & 127) * 16;
  int tid = threadIdx.x;
#pragma unroll
  for (int it = 0; it < 2; ++it) {
    int f = it * 256 + tid;
    int row = f >> 2, c4 = (f & 3) * 4;
    *(float4*)&cl[row * 16 + c4] =
        *(const float4*)&cmp[((size_t)(b * 128 + row)) * 2048 + t0 + c4];
  }
  __syncthreads();
  float acc[16];
#pragma unroll
  for (int i = 0; i < 16; ++i) acc[i] = 0.f;
  int d = tid;
  for (int m = 0; m < 128; ++m) {
    float rv = repm[(size_t)(b * 128 + m) * 256 + d];
    const float4* c4p = (const float4*)&cl[m * 16];
#pragma unroll
    for (int jj = 0; jj < 4; ++jj) {
      float4 c = c4p[jj];
      acc[jj * 4] += c.x * rv; acc[jj * 4 + 1] += c.y * rv;
      acc[jj * 4 + 2] += c.z * rv; acc[jj * 4 + 3] += c.w * rv;
    }
  }
  const float* xb = x + ((size_t)(b * 2048 + t0)) * 256 + d;
  float* ob = out + ((size_t)(b * 2048 + t0)) * 256 + d;
#pragma unroll
  for (int tt = 0; tt < 16; ++tt) ob[(size_t)tt * 256] = xb[(size_t)tt * 256] + acc[tt];
}

// ---------------------------------------------------------------------------
// K5: masked KLDiv mean loss (single block)
// ---------------------------------------------------------------------------
__global__ __launch_bounds__(1024) void k_loss(
    const float* __restrict__ logits, const float* __restrict__ lab,
    const unsigned char* __restrict__ mask, float* __restrict__ out_loss) {
  __shared__ float rs[1024], rc[1024];
  int tid = threadIdx.x;
  float sum = 0.f, cnt = 0.f;
  for (int p = tid; p < 8192; p += 1024) {
    float l0 = logits[(size_t)p * 2], l1 = logits[(size_t)p * 2 + 1];
    float a0 = lab[(size_t)p * 2], a1 = lab[(size_t)p * 2 + 1];
    float mx = fmaxf(l0, l1);
    float lse = mx + logf(expf(l0 - mx) + expf(l1 - mx));
    float pw = 0.f;
    if (a0 > 0.f) pw += a0 * logf(fmaxf(a0, 1e-38f));
    if (a1 > 0.f) pw += a1 * logf(fmaxf(a1, 1e-38f));
    pw -= a0 * (l0 - lse) + a1 * (l1 - lse);
    if (mask[p]) { sum += pw; cnt += 1.f; }
  }
  rs[tid] = sum; rc[tid] = cnt;
  __syncthreads();
  for (int s = 512; s > 0; s >>= 1) {
    if (tid < s) { rs[tid] += rs[tid + s]; rc[tid] += rc[tid + s]; }
    __syncthreads();
  }
  if (tid == 0) *out_loss = rs[0] / (rc[0] * 2.0f);
}

// ---------------------------------------------------------------------------
extern "C" void kernel_launch(void* const* d_in, const int* in_sizes, int n_in,
                              void* d_out, int out_size, void* d_ws, size_t ws_size,
                              hipStream_t stream) {
  (void)in_sizes; (void)n_in; (void)out_size; (void)ws_size;
  const float* head = (const float*)d_in[0];
  const float* tail = (const float*)d_in[1];
  // d_in[2] = lens (uniform L=16) -- unused
  const float* x = (const float*)d_in[3];
  const float* cmp = (const float*)d_in[4];
  const float* lab = (const float*)d_in[5];
  const unsigned char* lmask = (const unsigned char*)d_in[6];
  const float* w1 = (const float*)d_in[7];
  const float* b1 = (const float*)d_in[8];
  const float* w2 = (const float*)d_in[9];
  const float* b2 = (const float*)d_in[10];
  float* out = (float*)d_out;

  char* ws = (char*)d_ws;
  size_t off = 0;
  auto alloc = [&](size_t bytes) -> void* {
    void* p = ws + off; off += (bytes + 255) & ~(size_t)255; return p;
  };
  unsigned short* xt = (unsigned short*)alloc(4ull * 256 * 2048 * 2);
  unsigned short* w1t = (unsigned short*)alloc(256ull * 768 * 2);
  float* hrep = (float*)alloc(8192ull * 256 * 4);
  float* trep = (float*)alloc(8192ull * 256 * 4);
  unsigned short* featb = (unsigned short*)alloc(8192ull * 768 * 2);
  float* logits = (float*)alloc(8192ull * 2 * 4);
  float* refined = (float*)alloc(8192ull * 4);
  int* idxv = (int*)alloc(512 * 4);
  float* mvalv = (float*)alloc(512 * 4);
  int* cmaskv = (int*)alloc(512 * 4);
  int* njobs = (int*)alloc(256);
  int* jobs = (int*)alloc(8192 * 4);
  float* repm = (float*)alloc(512ull * 256 * 4);

  k_prep<<<304, 256, 0, stream>>>(x, w1, b2, xt, w1t, logits, njobs);
  k_gemm_rep<<<512, 512, 0, stream>>>(head, tail, xt, hrep, trep);
  k_feat<<<2048, 256, 0, stream>>>(hrep, trep, featb);
  k_gemm_mlp<<<512, 256, 0, stream>>>(featb, w1t, b1, w2, logits);
  k_select<<<2, 256, 0, stream>>>(logits, idxv, mvalv, cmaskv, njobs, jobs);
  k_refine<<<256, 1024, 0, stream>>>(njobs, jobs, head, tail, x, w1, b1, w2, b2, refined);
  k_repm<<<512, 256, 0, stream>>>(idxv, mvalv, cmaskv, refined, trep, repm);
  k_merge<<<512, 256, 0, stream>>>(cmp, repm, x, out);
  k_loss<<<1, 1024, 0, stream>>>(logits, lab, lmask, out + 4ull * 2048 * 256);
}